// Round 7
// baseline (163.514 us; speedup 1.0000x reference)
//
#include <hip/hip_runtime.h>
#include <cstdint>
#include <cstddef>

// x (B=8, C=64, S=32768) fp32; codebook (512, 64) fp32.
#define SPATIAL   32768
#define CHANNELS  64
#define NUM_EMB   512
#define NPOS      262144
#define OUT_ELEMS 16777216
#define LOSS_SCALE (1.25f / 16777216.0f)

typedef __attribute__((ext_vector_type(8))) short bf16x8;
typedef __attribute__((ext_vector_type(4))) float f32x4;

union b8u { int i[4]; bf16x8 v; };
union fiu { float f; unsigned u; };

// fp32 -> bf16 RNE (prep only)
__device__ __forceinline__ short f2bf_rne(float f) {
    fiu v; v.f = f;
    unsigned r = v.u + 0x7fffu + ((v.u >> 16) & 1u);
    return (short)(r >> 16);
}

// Prep: write codebook in MFMA fragment order + cbn[e] = -0.5*||cb_e||^2.
// Fragment layout: tile nt (16 entries), lane l = q*16+col:
//   cbfrag[nt*1024 + l*8 + j]       = bf16(cb[e0+col][q*8+j])      (K-half 0)
//   cbfrag[nt*1024 + 512 + l*8 + j] = bf16(cb[e0+col][32+q*8+j])   (K-half 1)
__global__ void vq_prep(const float* __restrict__ cb,
                        short* __restrict__ cbfrag,
                        float* __restrict__ cbn,
                        float* __restrict__ loss_slot) {
    int e = blockIdx.x * blockDim.x + threadIdx.x;
    if (e == 0) *loss_slot = 0.0f;
    if (e < NUM_EMB) {
        const int nt  = e >> 4;
        const int col = e & 15;
        float s = 0.0f;
#pragma unroll
        for (int q = 0; q < 4; ++q) {
#pragma unroll
            for (int j = 0; j < 8; ++j) {
                float v0 = cb[e * CHANNELS + q * 8 + j];
                float v1 = cb[e * CHANNELS + 32 + q * 8 + j];
                cbfrag[nt * 1024 + (q * 16 + col) * 8 + j]       = f2bf_rne(v0);
                cbfrag[nt * 1024 + 512 + (q * 16 + col) * 8 + j] = f2bf_rne(v1);
            }
        }
#pragma unroll
        for (int c = 0; c < CHANNELS; ++c) {
            float v = cb[e * CHANNELS + c];
            s = __builtin_fmaf(v, v, s);
        }
        cbn[e] = -0.5f * s;
    }
}

// R13 pass 1: argmin only (no epilogue). R12's swapped-operand MFMA +
// A01/A23 split-overlap kept; staging FIXED to cover all 64 KB of cbfrag
// via two 32 KB phases (R12 staged only half -- OOB ds_reads returned 0 for
// entries 256..511; passed only because any misassignment moves output by
// <=2/512 and loss by ~7e-5). Winners stored as u16 to workspace.
#define SCORE_LOOP(NT0, A, MBASE)                                             \
    _Pragma("unroll 2")                                                       \
    for (int nt = 0; nt < 16; ++nt) {                                         \
        const int ntg = (NT0) + nt;                                           \
        const short* sb = stageS + nt * 1024 + (lane << 3);                   \
        bf16x8 CB0 = *(const bf16x8*)sb;                                      \
        bf16x8 CB1 = *(const bf16x8*)(sb + 512);                              \
        f32x4 civ  = *(const f32x4*)(cbn + ntg * 16 + (q << 2));              \
        const unsigned encq = (unsigned)(511 - ntg * 16 - (q << 2));          \
        _Pragma("unroll")                                                     \
        for (int tt = 0; tt < 2; ++tt) {                                      \
            f32x4 acc = __builtin_amdgcn_mfma_f32_16x16x32_bf16(              \
                CB0, A[tt][0].v, civ, 0, 0, 0);                               \
            acc = __builtin_amdgcn_mfma_f32_16x16x32_bf16(                    \
                CB1, A[tt][1].v, acc, 0, 0, 0);                               \
            fiu p0, p1, p2, p3;                                               \
            p0.f = acc[0]; p0.u = (p0.u & MASK) | (encq - 0);                 \
            p1.f = acc[1]; p1.u = (p1.u & MASK) | (encq - 1);                 \
            p2.f = acc[2]; p2.u = (p2.u & MASK) | (encq - 2);                 \
            p3.f = acc[3]; p3.u = (p3.u & MASK) | (encq - 3);                 \
            float mm = fmaxf(fmaxf(p0.f, p1.f), fmaxf(p2.f, p3.f));           \
            mt[(MBASE) + tt] = fmaxf(mt[(MBASE) + tt], mm);                   \
        }                                                                     \
    }

__global__ __launch_bounds__(256) void vq_score(
    const float* __restrict__ x,
    const short* __restrict__ cbfrag,
    const float* __restrict__ cbn,
    unsigned short* __restrict__ cand) {
#pragma clang fp contract(off)
    __shared__ __align__(16) char smem[32768];   // 16-tile stage arena
    short* stageS = (short*)smem;

    const int tid  = threadIdx.x;
    const int wave = tid >> 6, lane = tid & 63;
    const int q    = lane >> 4, col = lane & 15;

    const int blockPos = blockIdx.x * 256;        // whole block same b
    const int b     = blockPos >> 15;
    const int sbase = blockPos & 32767;
    const float* xb = x + (size_t)b * (CHANNELS * SPATIAL);
    const int wbase = sbase + wave * 64;

    // ---- stage phase 0: tiles 0..15 (32 KB), issued first = oldest vmcnt ----
#pragma unroll
    for (int rd = 0; rd < 8; ++rd) {
        const int off = rd * 4096 + wave * 1024;
        __builtin_amdgcn_global_load_lds(
            (const __attribute__((address_space(1))) unsigned*)
                ((const char*)cbfrag + off + lane * 16),
            (__attribute__((address_space(3))) unsigned*)(smem + off), 16, 0, 0);
    }
    __builtin_amdgcn_sched_barrier(0);

    // ---- issue x raw loads: t0,t1 then t2,t3 ----
    unsigned r01[2][2][4][2], r23[2][2][4][2];
#pragma unroll
    for (int t = 0; t < 2; ++t) {
        const unsigned* pu = (const unsigned*)xb + (wbase + t * 16 + col);
#pragma unroll
        for (int kh = 0; kh < 2; ++kh)
#pragma unroll
            for (int jj = 0; jj < 4; ++jj) {
                r01[t][kh][jj][0] = pu[(size_t)(kh * 32 + q * 8 + 2 * jj + 0) * SPATIAL];
                r01[t][kh][jj][1] = pu[(size_t)(kh * 32 + q * 8 + 2 * jj + 1) * SPATIAL];
            }
    }
#pragma unroll
    for (int t = 0; t < 2; ++t) {
        const unsigned* pu = (const unsigned*)xb + (wbase + 32 + t * 16 + col);
#pragma unroll
        for (int kh = 0; kh < 2; ++kh)
#pragma unroll
            for (int jj = 0; jj < 4; ++jj) {
                r23[t][kh][jj][0] = pu[(size_t)(kh * 32 + q * 8 + 2 * jj + 0) * SPATIAL];
                r23[t][kh][jj][1] = pu[(size_t)(kh * 32 + q * 8 + 2 * jj + 1) * SPATIAL];
            }
    }
    __builtin_amdgcn_sched_barrier(0);

    // perm t0,t1 (vmcnt wait covers older staging loads too)
    b8u A01[2][2];
#pragma unroll
    for (int t = 0; t < 2; ++t)
#pragma unroll
        for (int kh = 0; kh < 2; ++kh)
#pragma unroll
            for (int jj = 0; jj < 4; ++jj)
                A01[t][kh].i[jj] = __builtin_amdgcn_perm(
                    r01[t][kh][jj][1], r01[t][kh][jj][0], 0x07060302u);

    __builtin_amdgcn_sched_barrier(0);
    __builtin_amdgcn_s_barrier();        // stage phase 0 visible
    __builtin_amdgcn_sched_barrier(0);

    float mt[4];
#pragma unroll
    for (int t = 0; t < 4; ++t) mt[t] = -3.4e38f;
    const unsigned MASK = 0xFFFFFE00u;

    // score tiles 0..15 with t01 (t23 x-reads stream underneath)
    SCORE_LOOP(0, A01, 0)

    // perm t2,t3, score tiles 0..15 with t23
    b8u A23[2][2];
#pragma unroll
    for (int t = 0; t < 2; ++t)
#pragma unroll
        for (int kh = 0; kh < 2; ++kh)
#pragma unroll
            for (int jj = 0; jj < 4; ++jj)
                A23[t][kh].i[jj] = __builtin_amdgcn_perm(
                    r23[t][kh][jj][1], r23[t][kh][jj][0], 0x07060302u);

    SCORE_LOOP(0, A23, 2)

    __syncthreads();   // all waves done reading tiles 0..15

    // ---- stage phase 1: tiles 16..31 into the same arena ----
#pragma unroll
    for (int rd = 0; rd < 8; ++rd) {
        const int off = rd * 4096 + wave * 1024;
        __builtin_amdgcn_global_load_lds(
            (const __attribute__((address_space(1))) unsigned*)
                ((const char*)cbfrag + 32768 + off + lane * 16),
            (__attribute__((address_space(3))) unsigned*)(smem + off), 16, 0, 0);
    }
    __syncthreads();   // own-wave vmcnt drained before barrier -> visible

    SCORE_LOOP(16, A01, 0)
    SCORE_LOOP(16, A23, 2)

    // ---- per-position winner (positions are lane-local cols; reduce over q) ----
#pragma unroll
    for (int t = 0; t < 4; ++t) {
        float v = mt[t];
        v = fmaxf(v, __shfl_xor(v, 16, 64));
        v = fmaxf(v, __shfl_xor(v, 32, 64));
        if (lane < 16) {
            fiu p; p.f = v;
            cand[blockPos + wave * 64 + t * 16 + lane] =
                (unsigned short)(511 - (int)(p.u & 511u));
        }
    }
}

// R13 pass 2: standalone epilogue stream. x is L3-resident from pass 1.
// 128 positions/block, 2 threads/pos x 32 channels; gather 8 lanes/row
// (one 128B line per row-half) into swizzled LDS, then consume.
// Loads and stores interleave per-instruction -> continuous HBM utilization.
#define POSB2 128
__global__ __launch_bounds__(256) void vq_epi(
    const float* __restrict__ x,
    const float* __restrict__ cb,
    const unsigned short* __restrict__ cand,
    float* __restrict__ out,
    float* __restrict__ loss_slot) {
#pragma clang fp contract(off)
    __shared__ float qbuf[2][POSB2 * 32];   // 32 KB
    __shared__ int   candL[POSB2];
    __shared__ float wsum[4];

    const int tid  = threadIdx.x;
    const int wave = tid >> 6, lane = tid & 63;

    const int blockPos = blockIdx.x * POSB2;      // 128 | 32768 -> same b
    const int b     = blockPos >> 15;
    const int sbase = blockPos & 32767;

    if (tid < POSB2) candL[tid] = cand[blockPos + tid];
    __syncthreads();

    const int half = tid >> 7;        // channel half (0,1)
    const int tloc = tid & 127;
    const int pos  = tloc;
    const int gr   = tloc >> 3;       // 16 row slots per iter
    const int gl   = tloc & 7;        // 16B sub-chunk within 128B half-row

    // gather: 128 rows x 128B (this half's 32 channels) into swizzled qbuf
#pragma unroll
    for (int rd = 0; rd < 8; ++rd) {
        const int r   = rd * 16 + gr;
        const int row = candL[r];
        f32x4 v = *((const f32x4*)(cb + (size_t)row * CHANNELS + half * 32) + gl);
        *((f32x4*)(&qbuf[half][r * 32 + ((gl ^ (r & 7)) << 2)])) = v;
    }
    __syncthreads();

    const float* px = x + (size_t)b * (CHANNELS * SPATIAL) + (sbase + pos)
                        + (size_t)(half * 32) * SPATIAL;
    float* op = out + (size_t)b * (CHANNELS * SPATIAL) + (sbase + pos)
                    + (size_t)(half * 32) * SPATIAL;
    float lsum = 0.0f;
#pragma unroll
    for (int j = 0; j < 8; ++j) {
        f32x4 qq = *((const f32x4*)(&qbuf[half][pos * 32 + ((j ^ (pos & 7)) << 2)]));
#pragma unroll
        for (int k = 0; k < 4; ++k) {
            const int ch = j * 4 + k;
            float xv = px[(size_t)ch * SPATIAL];
            float t2 = qq[k] - xv;
            op[(size_t)ch * SPATIAL] = xv + t2;
            lsum = __builtin_fmaf(t2, t2, lsum);
        }
    }

    // block loss reduction -> one atomic
#pragma unroll
    for (int off = 32; off > 0; off >>= 1) lsum += __shfl_down(lsum, off, 64);
    if (lane == 0) wsum[wave] = lsum;
    __syncthreads();
    if (tid == 0) {
        float bs = (wsum[0] + wsum[1]) + (wsum[2] + wsum[3]);
        atomicAdd(loss_slot, bs * LOSS_SCALE);
    }
}

extern "C" void kernel_launch(void* const* d_in, const int* in_sizes, int n_in,
                              void* d_out, int out_size, void* d_ws, size_t ws_size,
                              hipStream_t stream) {
    const float* x  = (const float*)d_in[0];
    const float* cb = (const float*)d_in[1];
    float* out = (float*)d_out;
    // workspace layout (requires ws_size >= ~580 KB):
    //   cbfrag: 32768 shorts (64 KB, fragment order)
    //   cbn:    512 floats   (2 KB)
    //   cand:   262144 u16   (512 KB)
    short* cbfrag = (short*)d_ws;
    float* cbn    = (float*)(cbfrag + NUM_EMB * CHANNELS);
    unsigned short* cand = (unsigned short*)(cbn + NUM_EMB);
    float* loss_slot = out + OUT_ELEMS;

    vq_prep<<<2, 256, 0, stream>>>(cb, cbfrag, cbn, loss_slot);
    vq_score<<<NPOS / 256, 256, 0, stream>>>(x, cbfrag, cbn, cand);
    vq_epi<<<NPOS / POSB2, 256, 0, stream>>>(x, cb, cand, out, loss_slot);
}

// Round 8
// 153.289 us; speedup vs baseline: 1.0667x; 1.0667x over previous
//
#include <hip/hip_runtime.h>
#include <cstdint>
#include <cstddef>

// x (B=8, C=64, S=32768) fp32; codebook (512, 64) fp32.
#define SPATIAL   32768
#define CHANNELS  64
#define NUM_EMB   512
#define NPOS      262144
#define OUT_ELEMS 16777216
#define BLOCK     256            // 4 waves; block covers 128 positions (32/wave)
#define POSB      128
#define LOSS_SCALE (1.25f / 16777216.0f)

typedef __attribute__((ext_vector_type(8))) short bf16x8;
typedef __attribute__((ext_vector_type(4))) float f32x4;

union b8u { int i[4]; bf16x8 v; };
union fiu { float f; unsigned u; };

// fp32 -> bf16 RNE (prep only)
__device__ __forceinline__ short f2bf_rne(float f) {
    fiu v; v.f = f;
    unsigned r = v.u + 0x7fffu + ((v.u >> 16) & 1u);
    return (short)(r >> 16);
}

// Prep: write codebook in MFMA fragment order + cbn[e] = -0.5*||cb_e||^2.
// Fragment layout: tile nt (16 entries), lane l = q*16+col:
//   cbfrag[nt*1024 + l*8 + j]       = bf16(cb[e0+col][q*8+j])      (K-half 0)
//   cbfrag[nt*1024 + 512 + l*8 + j] = bf16(cb[e0+col][32+q*8+j])   (K-half 1)
// Lane-contiguous 16B chunks -> directly global_load_lds-compatible (linear).
__global__ void vq_prep(const float* __restrict__ cb,
                        short* __restrict__ cbfrag,
                        float* __restrict__ cbn,
                        float* __restrict__ loss_slot) {
    int e = blockIdx.x * blockDim.x + threadIdx.x;
    if (e == 0) *loss_slot = 0.0f;
    if (e < NUM_EMB) {
        const int nt  = e >> 4;
        const int col = e & 15;
        float s = 0.0f;
#pragma unroll
        for (int q = 0; q < 4; ++q) {
#pragma unroll
            for (int j = 0; j < 8; ++j) {
                float v0 = cb[e * CHANNELS + q * 8 + j];
                float v1 = cb[e * CHANNELS + 32 + q * 8 + j];
                cbfrag[nt * 1024 + (q * 16 + col) * 8 + j]       = f2bf_rne(v0);
                cbfrag[nt * 1024 + 512 + (q * 16 + col) * 8 + j] = f2bf_rne(v1);
            }
        }
#pragma unroll
        for (int c = 0; c < CHANNELS; ++c) {
            float v = cb[e * CHANNELS + c];
            s = __builtin_fmaf(v, v, s);
        }
        cbn[e] = -0.5f * s;
    }
}

// R14: fused (R13 proved split loses ~20us of overlap) + REAL occupancy raise.
// All prior rounds ran at most 4 waves/SIMD resident (R9's extra waves queued
// behind 34KB LDS; R7 spilled at cap64; R8 inflated uncapped to 176).
// This config: 128 pos/block (t=2/wave) -> grid 2048 = 8 blocks/CU demanded;
// LDS ~17KB (stage dbuf 2x8KB, qbuf 16KB aliased, epilogue in 2 channel
// halves) and __launch_bounds__(256,6) (VGPR cap ~84, t=2 body needs ~75)
// -> 6 blocks/CU co-resident = 6 waves/SIMD (+50% residency).
// Score: single-pass CB (2 ds_read_b128 serve 4 MFMA), swapped-operand
// mfma(cb,x) with packed (score|511-e) max, 2-shfl reduction. Full 512
// entries staged across 8 chunks. Semantics identical to R11.
__global__ __launch_bounds__(BLOCK, 6) void vq_main(
    const float* __restrict__ x,
    const float* __restrict__ cb,
    const short* __restrict__ cbfrag,
    const float* __restrict__ cbn,
    float* __restrict__ out,
    float* __restrict__ loss_slot) {
#pragma clang fp contract(off)
    __shared__ __align__(16) char arena[16384];  // stage[2][8KB] | qbuf[128][32]f32
    __shared__ int   cand[POSB];
    __shared__ float wsum[4];

    short* stageS = (short*)arena;
    float* qbuf   = (float*)arena;

    const int tid  = threadIdx.x;
    const int wave = tid >> 6, lane = tid & 63;
    const int q    = lane >> 4, col = lane & 15;

    const int blockPos = blockIdx.x * POSB;       // 128 | 32768 -> whole block same b
    const int b     = blockPos >> 15;
    const int sbase = blockPos & 32767;
    const float* xb = x + (size_t)b * (CHANNELS * SPATIAL);
    const int wbase = sbase + wave * 32;

    // ---- stage chunk 0 (tiles 0..3, 8 KB) into buf 0; oldest in vmcnt ----
#pragma unroll
    for (int rd = 0; rd < 2; ++rd) {
        const int off = rd * 4096 + wave * 1024;
        __builtin_amdgcn_global_load_lds(
            (const __attribute__((address_space(1))) unsigned*)
                ((const char*)cbfrag + off + lane * 16),
            (__attribute__((address_space(3))) unsigned*)(arena + off), 16, 0, 0);
    }
    __builtin_amdgcn_sched_barrier(0);

    // ---- A fragments: wave covers 32 positions = 2 M-tiles of 16 ----
    b8u A[2][2];
#pragma unroll
    for (int t = 0; t < 2; ++t) {
        const unsigned* pu = (const unsigned*)xb + (wbase + t * 16 + col);
#pragma unroll
        for (int kh = 0; kh < 2; ++kh)
#pragma unroll
            for (int jj = 0; jj < 4; ++jj) {
                unsigned u0 = pu[(size_t)(kh * 32 + q * 8 + 2 * jj + 0) * SPATIAL];
                unsigned u1 = pu[(size_t)(kh * 32 + q * 8 + 2 * jj + 1) * SPATIAL];
                A[t][kh].i[jj] = __builtin_amdgcn_perm(u1, u0, 0x07060302u);
            }
    }

    __syncthreads();   // chunk 0 staged & visible (drains vmcnt incl. A-loads)

    float mt[2];
    mt[0] = -3.4e38f; mt[1] = -3.4e38f;
    const unsigned MASK = 0xFFFFFE00u;

    int buf = 0;
#pragma unroll 1
    for (int c = 0; c < 8; ++c) {
        if (c < 7) {
            // issue next chunk's staging into buf^1 (lands by end-of-iter barrier)
#pragma unroll
            for (int rd = 0; rd < 2; ++rd) {
                const int off = rd * 4096 + wave * 1024;
                __builtin_amdgcn_global_load_lds(
                    (const __attribute__((address_space(1))) unsigned*)
                        ((const char*)cbfrag + (c + 1) * 8192 + off + lane * 16),
                    (__attribute__((address_space(3))) unsigned*)
                        (arena + (buf ^ 1) * 8192 + off), 16, 0, 0);
            }
        }
#pragma unroll
        for (int k = 0; k < 4; ++k) {
            const int nt = c * 4 + k;
            const short* sb = stageS + buf * 4096 + k * 1024 + (lane << 3);
            bf16x8 CB0 = *(const bf16x8*)sb;
            bf16x8 CB1 = *(const bf16x8*)(sb + 512);
            f32x4 civ  = *(const f32x4*)(cbn + nt * 16 + (q << 2));
            const unsigned encq = (unsigned)(511 - nt * 16 - (q << 2));
#pragma unroll
            for (int tt = 0; tt < 2; ++tt) {
                f32x4 acc = __builtin_amdgcn_mfma_f32_16x16x32_bf16(CB0, A[tt][0].v, civ, 0, 0, 0);
                acc = __builtin_amdgcn_mfma_f32_16x16x32_bf16(CB1, A[tt][1].v, acc, 0, 0, 0);
                fiu p0, p1, p2, p3;
                p0.f = acc[0]; p0.u = (p0.u & MASK) | (encq - 0);
                p1.f = acc[1]; p1.u = (p1.u & MASK) | (encq - 1);
                p2.f = acc[2]; p2.u = (p2.u & MASK) | (encq - 2);
                p3.f = acc[3]; p3.u = (p3.u & MASK) | (encq - 3);
                float mm = fmaxf(fmaxf(p0.f, p1.f), fmaxf(p2.f, p3.f));
                mt[tt] = fmaxf(mt[tt], mm);
            }
        }
        __syncthreads();   // next chunk visible; buf free for overwrite
        buf ^= 1;
    }

    // ---- per-position winner: positions are lane-local cols; reduce over q ----
#pragma unroll
    for (int t = 0; t < 2; ++t) {
        float v = mt[t];
        v = fmaxf(v, __shfl_xor(v, 16, 64));
        v = fmaxf(v, __shfl_xor(v, 32, 64));
        if (lane < 16) {
            fiu p; p.f = v;
            cand[wave * 32 + t * 16 + lane] = 511 - (int)(p.u & 511u);
        }
    }
    __syncthreads();   // cand cross-wave; stage arena free for qbuf

    // ---- epilogue: out = fl(x + fl(q - x)), loss partial ----
    // Two 32-channel halves through one 16 KB swizzled qbuf.
    // Gather: 8 lanes per half-row (one 128B line each); consume: thread
    // (pos, sub) handles 16 channels.
    const int pos = tid & (POSB - 1);
    const int sub = tid >> 7;          // 16-channel quarter within the half
    const int gr  = tid >> 3;          // 32 rows per gather round
    const int gl  = tid & 7;           // 16B slice within 128B half-row
    const float* pxb = xb + (sbase + pos);
    float* opb = out + (size_t)b * (CHANNELS * SPATIAL) + (sbase + pos);
    float lsum = 0.0f;

#pragma unroll 1
    for (int cc = 0; cc < 2; ++cc) {
        // gather 128 rows x 128B (channels cc*32..+31) into swizzled qbuf
#pragma unroll
        for (int rd = 0; rd < 4; ++rd) {
            const int r   = rd * 32 + gr;
            const int row = cand[r];
            f32x4 v = *((const f32x4*)(cb + (size_t)row * CHANNELS + cc * 32) + gl);
            *((f32x4*)(qbuf + r * 32 + ((gl ^ (r & 7)) << 2))) = v;
        }
        __syncthreads();
        // consume: channels cc*32 + sub*16 .. +15 for position pos
#pragma unroll
        for (int j = 0; j < 4; ++j) {
            const int jj = sub * 4 + j;       // 16B slot within the 32-ch half
            f32x4 qq = *((const f32x4*)(qbuf + pos * 32 + ((jj ^ (pos & 7)) << 2)));
#pragma unroll
            for (int k = 0; k < 4; ++k) {
                const int ch = cc * 32 + jj * 4 + k;
                float xv = pxb[(size_t)ch * SPATIAL];
                float t2 = qq[k] - xv;
                opb[(size_t)ch * SPATIAL] = xv + t2;
                lsum = __builtin_fmaf(t2, t2, lsum);
            }
        }
        if (cc == 0) __syncthreads();   // qbuf reused by next half
    }

    // block loss reduction -> one atomic
#pragma unroll
    for (int off = 32; off > 0; off >>= 1) lsum += __shfl_down(lsum, off, 64);
    if (lane == 0) wsum[wave] = lsum;
    __syncthreads();
    if (tid == 0) {
        float bs = (wsum[0] + wsum[1]) + (wsum[2] + wsum[3]);
        atomicAdd(loss_slot, bs * LOSS_SCALE);
    }
}

extern "C" void kernel_launch(void* const* d_in, const int* in_sizes, int n_in,
                              void* d_out, int out_size, void* d_ws, size_t ws_size,
                              hipStream_t stream) {
    const float* x  = (const float*)d_in[0];
    const float* cb = (const float*)d_in[1];
    float* out = (float*)d_out;
    short* cbfrag = (short*)d_ws;                          // 64 KB, fragment order
    float* cbn    = (float*)(cbfrag + NUM_EMB * CHANNELS); // 512 floats
    float* loss_slot = out + OUT_ELEMS;

    vq_prep<<<2, 256, 0, stream>>>(cb, cbfrag, cbn, loss_slot);
    vq_main<<<NPOS / POSB, BLOCK, 0, stream>>>(x, cb, cbfrag, cbn, out, loss_slot);
}

// Round 9
// 150.915 us; speedup vs baseline: 1.0835x; 1.0157x over previous
//
#include <hip/hip_runtime.h>
#include <cstdint>
#include <cstddef>

// x (B=8, C=64, S=32768) fp32; codebook (512, 64) fp32.
#define SPATIAL   32768
#define CHANNELS  64
#define NUM_EMB   512
#define NPOS      262144
#define OUT_ELEMS 16777216
#define BLOCK     512            // 8 waves; block covers 256 positions (32/wave)
#define POSB      256
#define LOSS_SCALE (1.25f / 16777216.0f)

typedef __attribute__((ext_vector_type(8))) short bf16x8;
typedef __attribute__((ext_vector_type(4))) float f32x4;

union b8u { int i[4]; bf16x8 v; };
union fiu { float f; unsigned u; };

// fp32 -> bf16 RNE (prep only)
__device__ __forceinline__ short f2bf_rne(float f) {
    fiu v; v.f = f;
    unsigned r = v.u + 0x7fffu + ((v.u >> 16) & 1u);
    return (short)(r >> 16);
}

// Prep: write codebook in MFMA fragment order + cbn[e] = -0.5*||cb_e||^2.
// Fragment layout: tile nt (16 entries), lane l = q*16+col:
//   cbfrag[nt*1024 + l*8 + j]       = bf16(cb[e0+col][q*8+j])      (K-half 0)
//   cbfrag[nt*1024 + 512 + l*8 + j] = bf16(cb[e0+col][32+q*8+j])   (K-half 1)
__global__ void vq_prep(const float* __restrict__ cb,
                        short* __restrict__ cbfrag,
                        float* __restrict__ cbn,
                        float* __restrict__ loss_slot) {
    int e = blockIdx.x * blockDim.x + threadIdx.x;
    if (e == 0) *loss_slot = 0.0f;
    if (e < NUM_EMB) {
        const int nt  = e >> 4;
        const int col = e & 15;
        float s = 0.0f;
#pragma unroll
        for (int q = 0; q < 4; ++q) {
#pragma unroll
            for (int j = 0; j < 8; ++j) {
                float v0 = cb[e * CHANNELS + q * 8 + j];
                float v1 = cb[e * CHANNELS + 32 + q * 8 + j];
                cbfrag[nt * 1024 + (q * 16 + col) * 8 + j]       = f2bf_rne(v0);
                cbfrag[nt * 1024 + 512 + (q * 16 + col) * 8 + j] = f2bf_rne(v1);
            }
        }
#pragma unroll
        for (int c = 0; c < CHANNELS; ++c) {
            float v = cb[e * CHANNELS + c];
            s = __builtin_fmaf(v, v, s);
        }
        cbn[e] = -0.5f * s;
    }
}

// R15: 8 waves/SIMD with UNCHANGED per-position overhead. R14 failed because
// POSB=128 doubled staging/barrier/ds_read cost per position; this config
// (BLOCK=512, t=2/wave, POSB=256) keeps R11/R12's amortization (64KB staged
// per 256 pos) while total waves go 4096 -> 8192 = 8/SIMD, 4 blocks/CU
// independently phased. t=2 body measured 40 VGPR in R14 (fits 8 waves/SIMD);
// LDS ~34KB fits 4 blocks/CU. Score: swapped-operand mfma(cb,x), packed
// (score|511-e) max, 2-shfl winner. Full 512 entries, 8x8KB staged chunks,
// double-buffered. Semantics identical to R11.
__global__ __launch_bounds__(BLOCK, 6) void vq_main(
    const float* __restrict__ x,
    const float* __restrict__ cb,
    const short* __restrict__ cbfrag,
    const float* __restrict__ cbn,
    float* __restrict__ out,
    float* __restrict__ loss_slot) {
#pragma clang fp contract(off)
    __shared__ __align__(16) char arena[32768];  // stage[2][8KB] | qbuf[256][32]f32
    __shared__ int   cand[POSB];
    __shared__ float wsum[8];

    short* stageS = (short*)arena;
    float* qbuf   = (float*)arena;

    const int tid  = threadIdx.x;
    const int wave = tid >> 6, lane = tid & 63;
    const int q    = lane >> 4, col = lane & 15;

    const int blockPos = blockIdx.x * POSB;       // 256 | 32768 -> whole block same b
    const int b     = blockPos >> 15;
    const int sbase = blockPos & 32767;
    const float* xb = x + (size_t)b * (CHANNELS * SPATIAL);
    const int wbase = sbase + wave * 32;

    // ---- stage chunk 0 (tiles 0..3, 8 KB): one gload_lds per thread ----
    __builtin_amdgcn_global_load_lds(
        (const __attribute__((address_space(1))) unsigned*)
            ((const char*)cbfrag + tid * 16),
        (__attribute__((address_space(3))) unsigned*)(arena + tid * 16), 16, 0, 0);
    __builtin_amdgcn_sched_barrier(0);

    // ---- A fragments: wave covers 32 positions = 2 M-tiles of 16 ----
    b8u A[2][2];
#pragma unroll
    for (int t = 0; t < 2; ++t) {
        const unsigned* pu = (const unsigned*)xb + (wbase + t * 16 + col);
#pragma unroll
        for (int kh = 0; kh < 2; ++kh)
#pragma unroll
            for (int jj = 0; jj < 4; ++jj) {
                unsigned u0 = pu[(size_t)(kh * 32 + q * 8 + 2 * jj + 0) * SPATIAL];
                unsigned u1 = pu[(size_t)(kh * 32 + q * 8 + 2 * jj + 1) * SPATIAL];
                A[t][kh].i[jj] = __builtin_amdgcn_perm(u1, u0, 0x07060302u);
            }
    }

    __syncthreads();   // chunk 0 staged & visible (drains vmcnt incl. A-loads)

    float mt[2];
    mt[0] = -3.4e38f; mt[1] = -3.4e38f;
    const unsigned MASK = 0xFFFFFE00u;

    int buf = 0;
#pragma unroll 1
    for (int c = 0; c < 8; ++c) {
        if (c < 7) {
            // issue next chunk's staging into buf^1 (lands by end-of-iter barrier)
            __builtin_amdgcn_global_load_lds(
                (const __attribute__((address_space(1))) unsigned*)
                    ((const char*)cbfrag + (c + 1) * 8192 + tid * 16),
                (__attribute__((address_space(3))) unsigned*)
                    (arena + (buf ^ 1) * 8192 + tid * 16), 16, 0, 0);
        }
#pragma unroll
        for (int k = 0; k < 4; ++k) {
            const int nt = c * 4 + k;
            const short* sb = stageS + buf * 4096 + k * 1024 + (lane << 3);
            bf16x8 CB0 = *(const bf16x8*)sb;
            bf16x8 CB1 = *(const bf16x8*)(sb + 512);
            f32x4 civ  = *(const f32x4*)(cbn + nt * 16 + (q << 2));
            const unsigned encq = (unsigned)(511 - nt * 16 - (q << 2));
#pragma unroll
            for (int tt = 0; tt < 2; ++tt) {
                f32x4 acc = __builtin_amdgcn_mfma_f32_16x16x32_bf16(CB0, A[tt][0].v, civ, 0, 0, 0);
                acc = __builtin_amdgcn_mfma_f32_16x16x32_bf16(CB1, A[tt][1].v, acc, 0, 0, 0);
                fiu p0, p1, p2, p3;
                p0.f = acc[0]; p0.u = (p0.u & MASK) | (encq - 0);
                p1.f = acc[1]; p1.u = (p1.u & MASK) | (encq - 1);
                p2.f = acc[2]; p2.u = (p2.u & MASK) | (encq - 2);
                p3.f = acc[3]; p3.u = (p3.u & MASK) | (encq - 3);
                float mm = fmaxf(fmaxf(p0.f, p1.f), fmaxf(p2.f, p3.f));
                mt[tt] = fmaxf(mt[tt], mm);
            }
        }
        __syncthreads();   // next chunk visible; buf free for overwrite
        buf ^= 1;
    }

    // ---- per-position winner: positions are lane-local cols; reduce over q ----
#pragma unroll
    for (int t = 0; t < 2; ++t) {
        float v = mt[t];
        v = fmaxf(v, __shfl_xor(v, 16, 64));
        v = fmaxf(v, __shfl_xor(v, 32, 64));
        if (lane < 16) {
            fiu p; p.f = v;
            cand[wave * 32 + t * 16 + lane] = 511 - (int)(p.u & 511u);
        }
    }
    __syncthreads();   // cand cross-wave; stage arena free for qbuf

    // ---- epilogue: out = fl(x + fl(q - x)), loss partial ----
    // Two 32-channel halves through one 32 KB swizzled qbuf (256 rows).
    // Gather: 8 lanes per half-row (one 128B line each), 4 rounds;
    // consume: thread (pos, hh) handles 16 channels per half.
    const int pos = tid & (POSB - 1);
    const int hh  = tid >> 8;          // 16-channel quarter within the half
    const int gr  = tid >> 3;          // 64 rows per gather round
    const int gl  = tid & 7;           // 16B slice within 128B half-row
    const float* pxb = xb + (sbase + pos);
    float* opb = out + (size_t)b * (CHANNELS * SPATIAL) + (sbase + pos);
    float lsum = 0.0f;

#pragma unroll 1
    for (int cc = 0; cc < 2; ++cc) {
        // gather 256 rows x 128B (channels cc*32..+31) into swizzled qbuf
#pragma unroll
        for (int rd = 0; rd < 4; ++rd) {
            const int r   = rd * 64 + gr;
            const int row = cand[r];
            f32x4 v = *((const f32x4*)(cb + (size_t)row * CHANNELS + cc * 32) + gl);
            *((f32x4*)(qbuf + r * 32 + ((gl ^ (r & 7)) << 2))) = v;
        }
        __syncthreads();
        // consume: channels cc*32 + hh*16 .. +15 for position pos
#pragma unroll
        for (int j = 0; j < 4; ++j) {
            const int jj = hh * 4 + j;        // 16B slot within the 32-ch half
            f32x4 qq = *((const f32x4*)(qbuf + pos * 32 + ((jj ^ (pos & 7)) << 2)));
#pragma unroll
            for (int k = 0; k < 4; ++k) {
                const int ch = cc * 32 + jj * 4 + k;
                float xv = pxb[(size_t)ch * SPATIAL];
                float t2 = qq[k] - xv;
                opb[(size_t)ch * SPATIAL] = xv + t2;
                lsum = __builtin_fmaf(t2, t2, lsum);
            }
        }
        if (cc == 0) __syncthreads();   // qbuf reused by next half
    }

    // block loss reduction -> one atomic
#pragma unroll
    for (int off = 32; off > 0; off >>= 1) lsum += __shfl_down(lsum, off, 64);
    if (lane == 0) wsum[wave] = lsum;
    __syncthreads();
    if (tid == 0) {
        float bs = ((wsum[0] + wsum[1]) + (wsum[2] + wsum[3]))
                 + ((wsum[4] + wsum[5]) + (wsum[6] + wsum[7]));
        atomicAdd(loss_slot, bs * LOSS_SCALE);
    }
}

extern "C" void kernel_launch(void* const* d_in, const int* in_sizes, int n_in,
                              void* d_out, int out_size, void* d_ws, size_t ws_size,
                              hipStream_t stream) {
    const float* x  = (const float*)d_in[0];
    const float* cb = (const float*)d_in[1];
    float* out = (float*)d_out;
    short* cbfrag = (short*)d_ws;                          // 64 KB, fragment order
    float* cbn    = (float*)(cbfrag + NUM_EMB * CHANNELS); // 512 floats
    float* loss_slot = out + OUT_ELEMS;

    vq_prep<<<2, 256, 0, stream>>>(cb, cbfrag, cbn, loss_slot);
    vq_main<<<NPOS / POSB, BLOCK, 0, stream>>>(x, cb, cbfrag, cbn, out, loss_slot);
}

// Round 11
// 137.535 us; speedup vs baseline: 1.1889x; 1.0973x over previous
//
#include <hip/hip_runtime.h>
#include <cstdint>
#include <cstddef>

// x (B=8, C=64, S=32768) fp32; codebook (512, 64) fp32.
#define SPATIAL   32768
#define CHANNELS  64
#define NUM_EMB   512
#define NPOS      262144
#define OUT_ELEMS 16777216
#define BLOCK     256            // 4 waves; block covers 256 positions (64/wave)
#define POSB      256
#define LOSS_SCALE (1.25f / 16777216.0f)

typedef __attribute__((ext_vector_type(8))) short bf16x8;
typedef __attribute__((ext_vector_type(4))) float f32x4;

union b8u { int i[4]; bf16x8 v; };
union fiu { float f; unsigned u; };

__device__ __forceinline__ float max3f(float a, float b, float c) {
    float d;
    asm("v_max3_f32 %0, %1, %2, %3" : "=v"(d) : "v"(a), "v"(b), "v"(c));
    return d;
}

// fp32 -> bf16 RNE (prep only)
__device__ __forceinline__ short f2bf_rne(float f) {
    fiu v; v.f = f;
    unsigned r = v.u + 0x7fffu + ((v.u >> 16) & 1u);
    return (short)(r >> 16);
}

// Prep: write codebook in MFMA fragment order + cbn[e] = -0.5*||cb_e||^2.
// Fragment layout: tile nt (16 entries), lane l = q*16+col:
//   cbfrag[nt*1024 + l*8 + j]       = bf16(cb[e0+col][q*8+j])      (K-half 0)
//   cbfrag[nt*1024 + 512 + l*8 + j] = bf16(cb[e0+col][32+q*8+j])   (K-half 1)
__global__ void vq_prep(const float* __restrict__ cb,
                        short* __restrict__ cbfrag,
                        float* __restrict__ cbn,
                        float* __restrict__ loss_slot) {
    int e = blockIdx.x * blockDim.x + threadIdx.x;
    if (e == 0) *loss_slot = 0.0f;
    if (e < NUM_EMB) {
        const int nt  = e >> 4;
        const int col = e & 15;
        float s = 0.0f;
#pragma unroll
        for (int q = 0; q < 4; ++q) {
#pragma unroll
            for (int j = 0; j < 8; ++j) {
                float v0 = cb[e * CHANNELS + q * 8 + j];
                float v1 = cb[e * CHANNELS + 32 + q * 8 + j];
                cbfrag[nt * 1024 + (q * 16 + col) * 8 + j]       = f2bf_rne(v0);
                cbfrag[nt * 1024 + 512 + (q * 16 + col) * 8 + j] = f2bf_rne(v1);
            }
        }
#pragma unroll
        for (int c = 0; c < CHANNELS; ++c) {
            float v = cb[e * CHANNELS + c];
            s = __builtin_fmaf(v, v, s);
        }
        cbn[e] = -0.5f * s;
    }
}

// R16b: R16 resubmit (R10 bench was a container infra failure) with one
// audit fix: the epilogue cc-loop was `#pragma unroll 1`, making
// xr[t][cc][jj][s] a RUNTIME-indexed register array -> scratch allocation
// (rule #20), defeating the register-x epilogue. Now fully unrolled: every
// xr index is compile-time.
//  (1) register-x epilogue: A-phase raw dwords (64/lane = whole x-tile) stay
//      live through the score loop; out = x+(q-x) from regs. Epilogue x
//      re-read deleted. q via proven gather->swizzled qbuf.
//  (2) cbn staged to LDS once (2 KB): no per-iter global cbn loads.
//  (3) v_max3_f32: packed-max tail 8 -> 6 VALU per acc quartet.
//  (4) R11's proven double-buffered 8x8KB chunk staging, full 512 entries.
// Winner selection bit-identical to R11 (packed (score|511-e) max chain).
__global__ __launch_bounds__(BLOCK, 4) void vq_main(
    const float* __restrict__ x,
    const float* __restrict__ cb,
    const short* __restrict__ cbfrag,
    const float* __restrict__ cbn,
    float* __restrict__ out,
    float* __restrict__ loss_slot) {
#pragma clang fp contract(off)
    __shared__ __align__(16) char arena[32768];  // [0,16K) stage dbuf | all 32K qbuf
    __shared__ float cbnL[NUM_EMB];
    __shared__ int   cand[POSB];
    __shared__ float wsum[4];

    short* stageS = (short*)arena;
    float* qbuf   = (float*)arena;

    const int tid  = threadIdx.x;
    const int wave = tid >> 6, lane = tid & 63;
    const int q    = lane >> 4, col = lane & 15;

    const int blockPos = blockIdx.x * POSB;       // 256 | 32768 -> whole block same b
    const int b     = blockPos >> 15;
    const int sbase = blockPos & 32767;
    const float* xb = x + (size_t)b * (CHANNELS * SPATIAL);
    const int wbase = sbase + wave * 64;

    // ---- stage chunk 0 (tiles 0..3, 8 KB) + cbn (2 KB); oldest in vmcnt ----
#pragma unroll
    for (int rd = 0; rd < 2; ++rd) {
        __builtin_amdgcn_global_load_lds(
            (const __attribute__((address_space(1))) unsigned*)
                ((const char*)cbfrag + rd * 4096 + tid * 16),
            (__attribute__((address_space(3))) unsigned*)
                (arena + rd * 4096 + tid * 16), 16, 0, 0);
    }
#pragma unroll
    for (int rd = 0; rd < 2; ++rd) {
        __builtin_amdgcn_global_load_lds(
            (const __attribute__((address_space(1))) unsigned*)(cbn + rd * 256 + tid),
            (__attribute__((address_space(3))) unsigned*)(cbnL + rd * 256 + tid),
            4, 0, 0);
    }
    __builtin_amdgcn_sched_barrier(0);

    // ---- A raw loads: whole x-tile (64 dwords/lane) -- kept live to the end ----
    unsigned xr[4][2][4][2];
#pragma unroll
    for (int t = 0; t < 4; ++t) {
        const unsigned* pu = (const unsigned*)xb + (wbase + t * 16 + col);
#pragma unroll
        for (int kh = 0; kh < 2; ++kh)
#pragma unroll
            for (int jj = 0; jj < 4; ++jj) {
                xr[t][kh][jj][0] = pu[(size_t)(kh * 32 + q * 8 + 2 * jj + 0) * SPATIAL];
                xr[t][kh][jj][1] = pu[(size_t)(kh * 32 + q * 8 + 2 * jj + 1) * SPATIAL];
            }
    }

    // bf16 fragments by truncation: one v_perm packs 2 values
    b8u A[4][2];
#pragma unroll
    for (int t = 0; t < 4; ++t)
#pragma unroll
        for (int kh = 0; kh < 2; ++kh)
#pragma unroll
            for (int jj = 0; jj < 4; ++jj)
                A[t][kh].i[jj] = __builtin_amdgcn_perm(
                    xr[t][kh][jj][1], xr[t][kh][jj][0], 0x07060302u);

    __syncthreads();   // chunk 0 + cbn staged & visible (drains vmcnt)

    float mt[4];
#pragma unroll
    for (int t = 0; t < 4; ++t) mt[t] = -3.4e38f;
    const unsigned MASK = 0xFFFFFE00u;

    int buf = 0;
#pragma unroll 1
    for (int c = 0; c < 8; ++c) {
        if (c < 7) {
            // issue next chunk into buf^1 (lands by end-of-iter barrier)
#pragma unroll
            for (int rd = 0; rd < 2; ++rd) {
                __builtin_amdgcn_global_load_lds(
                    (const __attribute__((address_space(1))) unsigned*)
                        ((const char*)cbfrag + (c + 1) * 8192 + rd * 4096 + tid * 16),
                    (__attribute__((address_space(3))) unsigned*)
                        (arena + (buf ^ 1) * 8192 + rd * 4096 + tid * 16), 16, 0, 0);
            }
        }
#pragma unroll
        for (int k = 0; k < 4; ++k) {
            const int nt = c * 4 + k;
            const short* sb = stageS + buf * 4096 + k * 1024 + (lane << 3);
            bf16x8 CB0 = *(const bf16x8*)sb;
            bf16x8 CB1 = *(const bf16x8*)(sb + 512);
            f32x4 civ  = *(const f32x4*)(cbnL + nt * 16 + (q << 2)); // LDS broadcast
            const unsigned encq = (unsigned)(511 - nt * 16 - (q << 2));
#pragma unroll
            for (int tt = 0; tt < 4; ++tt) {
                f32x4 acc = __builtin_amdgcn_mfma_f32_16x16x32_bf16(CB0, A[tt][0].v, civ, 0, 0, 0);
                acc = __builtin_amdgcn_mfma_f32_16x16x32_bf16(CB1, A[tt][1].v, acc, 0, 0, 0);
                fiu p0, p1, p2, p3;
                p0.f = acc[0]; p0.u = (p0.u & MASK) | (encq - 0);
                p1.f = acc[1]; p1.u = (p1.u & MASK) | (encq - 1);
                p2.f = acc[2]; p2.u = (p2.u & MASK) | (encq - 2);
                p3.f = acc[3]; p3.u = (p3.u & MASK) | (encq - 3);
                float pm = max3f(p0.f, p1.f, p2.f);
                mt[tt] = max3f(pm, p3.f, mt[tt]);
            }
        }
        __syncthreads();   // next chunk visible; buf free for overwrite
        buf ^= 1;
    }

    // ---- per-position winner: positions are lane-local cols; reduce over q ----
#pragma unroll
    for (int t = 0; t < 4; ++t) {
        float v = mt[t];
        v = fmaxf(v, __shfl_xor(v, 16, 64));
        v = fmaxf(v, __shfl_xor(v, 32, 64));
        if (lane < 16) {
            fiu p; p.f = v;
            cand[wave * 64 + t * 16 + lane] = 511 - (int)(p.u & 511u);
        }
    }
    __syncthreads();   // cand cross-wave; stage arena free for qbuf

    // ---- epilogue: out = fl(x + fl(q - x)) from REGISTER x, loss partial ----
    // Two 32-channel halves, FULLY UNROLLED (cc compile-time -> xr stays in
    // registers; rule #20). Gather: 8 lanes/row (one 128B line each) into
    // slot-XOR-swizzled qbuf; consume: MFMA lane layout reads its own slots.
    const int gr = tid >> 3;          // 32 slots per gather round
    const int gl = tid & 7;           // 16B sub-chunk within 128B half-row
    float* opb = out + (size_t)b * (CHANNELS * SPATIAL) + (sbase + wave * 64 + col);
    float lsum = 0.0f;

#pragma unroll
    for (int cc = 0; cc < 2; ++cc) {
        // gather 256 rows x 128B (channels cc*32..+31) into swizzled qbuf
#pragma unroll
        for (int rd = 0; rd < 8; ++rd) {
            const int r   = rd * 32 + gr;
            const int row = cand[r];
            f32x4 v = *((const f32x4*)(cb + (size_t)row * CHANNELS + cc * 32) + gl);
            *((f32x4*)(qbuf + r * 32 + ((gl ^ (r & 7)) << 2))) = v;
        }
        __syncthreads();
        // consume: lane (q,col) of wave w, tile t -> slot p, channels cc*32+q*8..+7
#pragma unroll
        for (int t = 0; t < 4; ++t) {
            const int p  = wave * 64 + t * 16 + col;
            const int c0 = (2 * q) ^ (p & 7);
            const int c1 = (2 * q + 1) ^ (p & 7);
            f32x4 qq0 = *((const f32x4*)(qbuf + p * 32 + (c0 << 2)));
            f32x4 qq1 = *((const f32x4*)(qbuf + p * 32 + (c1 << 2)));
            float* opt = opb + t * 16;
#pragma unroll
            for (int jj = 0; jj < 4; ++jj) {
#pragma unroll
                for (int s = 0; s < 2; ++s) {
                    const int w  = 2 * jj + s;           // 0..7
                    const int ch = cc * 32 + q * 8 + w;
                    float xv = __uint_as_float(xr[t][cc][jj][s]);
                    float qv = (w < 4) ? qq0[w] : qq1[w - 4];
                    float t2 = qv - xv;
                    opt[(size_t)ch * SPATIAL] = xv + t2;
                    lsum = __builtin_fmaf(t2, t2, lsum);
                }
            }
        }
        if (cc == 0) __syncthreads();   // qbuf reused by next half
    }

    // block loss reduction -> one atomic
#pragma unroll
    for (int off = 32; off > 0; off >>= 1) lsum += __shfl_down(lsum, off, 64);
    if (lane == 0) wsum[wave] = lsum;
    __syncthreads();
    if (tid == 0) {
        float bs = (wsum[0] + wsum[1]) + (wsum[2] + wsum[3]);
        atomicAdd(loss_slot, bs * LOSS_SCALE);
    }
}

extern "C" void kernel_launch(void* const* d_in, const int* in_sizes, int n_in,
                              void* d_out, int out_size, void* d_ws, size_t ws_size,
                              hipStream_t stream) {
    const float* x  = (const float*)d_in[0];
    const float* cb = (const float*)d_in[1];
    float* out = (float*)d_out;
    short* cbfrag = (short*)d_ws;                          // 64 KB, fragment order
    float* cbn    = (float*)(cbfrag + NUM_EMB * CHANNELS); // 512 floats
    float* loss_slot = out + OUT_ELEMS;

    vq_prep<<<2, 256, 0, stream>>>(cb, cbfrag, cbn, loss_slot);
    vq_main<<<NPOS / POSB, BLOCK, 0, stream>>>(x, cb, cbfrag, cbn, out, loss_slot);
}